// Round 4
// baseline (58.742 us; speedup 1.0000x reference)
//
#include <hip/hip_runtime.h>
#include <math.h>

// out = log( sum_{m,k} W[m][k] * x^k * b^m ),  x = a*a/4.
// x>0, b>0 => every term positive => no log-space stabilization needed
// (max coeff 0.859, sum in [0.86, ~1e3], all comfortably fp32).
//
// W[m][k] via pure rational recurrences at COMPILE TIME; both loops fully
// unrolled so coefficients are inline 32-bit literals (no smem/LDS/sload).
//
// Truncation vs reference 20x20: rows decay ~5e-3 per m (and b^m < 1);
// inner terms decay super-geometrically past k ~ x_max (~5.5 here).
// MT=8, KT=14 -> truncation < 1e-9 abs; empirically absmax was identical
// (0.0078125, comparison noise) for full 20x20 vs 10x16.
//
// 2 elems/thread x 1024 blocks = 4096 waves (4/SIMD) for latency hiding.

#define MT 8
#define KT 14

struct Tbl { float w[MT][KT]; };

constexpr Tbl make_tbl() {
    Tbl t{};
    double p = 0.2734375 * 3.14159265358979323846;  // exp(CO[0])
    for (int m = 0; m < MT; ++m) {
        double wv = p;
        for (int k = 0; k < KT; ++k) {
            t.w[m][k] = (float)wv;
            wv *= (4.5 + k) / ((0.5 + k) * (2.0 * m + 5.0 + k) * (k + 1.0));
        }
        double num = (2.0 * m + 0.5) * (2.0 * m + 1.5);
        double den = 4.0 * (2.0 * m + 5.0) * (2.0 * m + 6.0) * (m + 1.0) * (m + 1.0);
        p *= num / den;  // exp(CO[m+1]-CO[m])
    }
    return t;
}

constexpr Tbl TBL = make_tbl();

__device__ __forceinline__ float ipe_one(float av, float bv) {
    float x = av * av * 0.25f;
    float acc = 0.0f;
#pragma unroll
    for (int m = MT - 1; m >= 0; --m) {
        float s = TBL.w[m][KT - 1];
#pragma unroll
        for (int k = KT - 2; k >= 0; --k) s = fmaf(s, x, TBL.w[m][k]);
        acc = fmaf(acc, bv, s);
    }
    return __logf(acc);
}

__global__ __launch_bounds__(256) void ipe_main(const float* __restrict__ a,
                                                const float* __restrict__ b,
                                                float* __restrict__ out, int n) {
    int base = (blockIdx.x * blockDim.x + threadIdx.x) * 2;
    if (base + 2 <= n) {
        float2 av = *reinterpret_cast<const float2*>(a + base);
        float2 bv = *reinterpret_cast<const float2*>(b + base);
        float x0 = av.x * av.x * 0.25f;
        float x1 = av.y * av.y * 0.25f;
        float acc0 = 0.0f, acc1 = 0.0f;
#pragma unroll
        for (int m = MT - 1; m >= 0; --m) {
            float c = TBL.w[m][KT - 1];
            float s0 = c, s1 = c;
#pragma unroll
            for (int k = KT - 2; k >= 0; --k) {
                float ck = TBL.w[m][k];  // compile-time constant -> inline literal
                s0 = fmaf(s0, x0, ck);
                s1 = fmaf(s1, x1, ck);
            }
            acc0 = fmaf(acc0, bv.x, s0);
            acc1 = fmaf(acc1, bv.y, s1);
        }
        float2 ov;
        ov.x = __logf(acc0);
        ov.y = __logf(acc1);
        *reinterpret_cast<float2*>(out + base) = ov;
    } else {
        for (int i = base; i < n; ++i) out[i] = ipe_one(a[i], b[i]);
    }
}

extern "C" void kernel_launch(void* const* d_in, const int* in_sizes, int n_in,
                              void* d_out, int out_size, void* d_ws, size_t ws_size,
                              hipStream_t stream) {
    const float* a = (const float*)d_in[0];
    const float* b = (const float*)d_in[1];
    float* out = (float*)d_out;
    int n = in_sizes[0];

    const int threads = 256;
    const int epb = threads * 2;
    int blocks = (n + epb - 1) / epb;
    hipLaunchKernelGGL(ipe_main, dim3(blocks), dim3(threads), 0, stream,
                       a, b, out, n);
}